// Round 12
// baseline (20299.854 us; speedup 1.0000x reference)
//
#include <hip/hip_runtime.h>

#define NP 262144
#define DI 128
#define KCL 512
#define NIT 10
#define NCH 1024      // chunks for the counting sort
#define CHS 256       // points per chunk (NCH*CHS == NP)

// Fast-math-immune fp32 NaN test.
__device__ __forceinline__ bool isnan_bits32(float x) {
  unsigned b = __float_as_uint(x);
  return (b & 0x7FFFFFFFu) > 0x7F800000u;
}

// numpy pairwise_sum of v[i]*v[i] for n=128 (numpy's 8-accumulator unrolled path).
__device__ __forceinline__ float np_pairwise128_sq(const float* v) {
  float r[8];
  #pragma unroll
  for (int j = 0; j < 8; ++j) r[j] = __fmul_rn(v[j], v[j]);
  #pragma unroll
  for (int t = 1; t < 16; ++t)
    #pragma unroll
    for (int j = 0; j < 8; ++j)
      r[j] = __fadd_rn(r[j], __fmul_rn(v[8 * t + j], v[8 * t + j]));
  float t01 = __fadd_rn(r[0], r[1]), t23 = __fadd_rn(r[2], r[3]);
  float t45 = __fadd_rn(r[4], r[5]), t67 = __fadd_rn(r[6], r[7]);
  return __fadd_rn(__fadd_rn(t01, t23), __fadd_rn(t45, t67));
}

// ---------------- init: C0 = X[:512]; cnorm[k] = np-pairwise of c*c ----------------
__global__ void k_init(const float* __restrict__ X, float* __restrict__ C,
                       float* __restrict__ cnorm) {
  int k = blockIdx.x, d = threadIdx.x;
  float v = X[(size_t)k * DI + d];
  C[(size_t)k * DI + d] = v;
  __shared__ float row[DI];
  row[d] = v;
  __syncthreads();
  if (d == 0) cnorm[k] = np_pairwise128_sq(row);
}

// ---------------- xnorm: once per run (X constant). Streaming 8-acc pairwise. ----------
__global__ void k_xnorm(const float* __restrict__ X, float* __restrict__ xnorm) {
  const int p = blockIdx.x * 256 + threadIdx.x;
  const float4* X4 = (const float4*)X + (size_t)p * 32;
  float r[8];
  {
    float4 q0 = X4[0], q1 = X4[1];
    r[0] = __fmul_rn(q0.x, q0.x); r[1] = __fmul_rn(q0.y, q0.y);
    r[2] = __fmul_rn(q0.z, q0.z); r[3] = __fmul_rn(q0.w, q0.w);
    r[4] = __fmul_rn(q1.x, q1.x); r[5] = __fmul_rn(q1.y, q1.y);
    r[6] = __fmul_rn(q1.z, q1.z); r[7] = __fmul_rn(q1.w, q1.w);
  }
  #pragma unroll
  for (int t = 1; t < 16; ++t) {
    float4 q0 = X4[2 * t], q1 = X4[2 * t + 1];
    r[0] = __fadd_rn(r[0], __fmul_rn(q0.x, q0.x));
    r[1] = __fadd_rn(r[1], __fmul_rn(q0.y, q0.y));
    r[2] = __fadd_rn(r[2], __fmul_rn(q0.z, q0.z));
    r[3] = __fadd_rn(r[3], __fmul_rn(q0.w, q0.w));
    r[4] = __fadd_rn(r[4], __fmul_rn(q1.x, q1.x));
    r[5] = __fadd_rn(r[5], __fmul_rn(q1.y, q1.y));
    r[6] = __fadd_rn(r[6], __fmul_rn(q1.z, q1.z));
    r[7] = __fadd_rn(r[7], __fmul_rn(q1.w, q1.w));
  }
  float t01 = __fadd_rn(r[0], r[1]), t23 = __fadd_rn(r[2], r[3]);
  float t45 = __fadd_rn(r[4], r[5]), t67 = __fadd_rn(r[6], r[7]);
  xnorm[p] = __fadd_rn(__fadd_rn(t01, t23), __fadd_rn(t45, t67));
}

// ---------------- assignment: x in registers, KU=4 chains; NO LDS ----------------
// R10 body (passed, absmax 0) with launch_bounds(256,1): lifts the 128-VGPR cap that
// forced x[128] to scratch in R10. C rows are wave-uniform float4 broadcasts (L2-hot).
__global__ __launch_bounds__(256, 1)
void k_assign_r(const float* __restrict__ X, const float* __restrict__ C,
                const float* __restrict__ cnorm, const float* __restrict__ xnorm,
                int* __restrict__ labels) {
  const int p = blockIdx.x * 256 + threadIdx.x;
  const float4* X4 = (const float4*)X + (size_t)p * 32;
  float x[DI];
  #pragma unroll
  for (int q = 0; q < 32; ++q) {
    float4 v = X4[q];
    x[4 * q + 0] = v.x; x[4 * q + 1] = v.y;
    x[4 * q + 2] = v.z; x[4 * q + 3] = v.w;
  }
  const float xn = xnorm[p];

  float best = 0.0f;
  int bestk = -1;
  int firstnan = 0x7fffffff;
  for (int k0 = 0; k0 < KCL; k0 += 4) {
    const float* C0 = C + (size_t)k0 * DI;
    float a0 = 0.0f, a1 = 0.0f, a2 = 0.0f, a3 = 0.0f;
    #pragma unroll
    for (int q = 0; q < 32; ++q) {
      float4 c0 = *(const float4*)(C0 + 0 * DI + 4 * q);
      float4 c1 = *(const float4*)(C0 + 1 * DI + 4 * q);
      float4 c2 = *(const float4*)(C0 + 2 * DI + 4 * q);
      float4 c3 = *(const float4*)(C0 + 3 * DI + 4 * q);
      a0 = __fmaf_rn(x[4 * q + 0], c0.x, a0); a0 = __fmaf_rn(x[4 * q + 1], c0.y, a0);
      a0 = __fmaf_rn(x[4 * q + 2], c0.z, a0); a0 = __fmaf_rn(x[4 * q + 3], c0.w, a0);
      a1 = __fmaf_rn(x[4 * q + 0], c1.x, a1); a1 = __fmaf_rn(x[4 * q + 1], c1.y, a1);
      a1 = __fmaf_rn(x[4 * q + 2], c1.z, a1); a1 = __fmaf_rn(x[4 * q + 3], c1.w, a1);
      a2 = __fmaf_rn(x[4 * q + 0], c2.x, a2); a2 = __fmaf_rn(x[4 * q + 1], c2.y, a2);
      a2 = __fmaf_rn(x[4 * q + 2], c2.z, a2); a2 = __fmaf_rn(x[4 * q + 3], c2.w, a2);
      a3 = __fmaf_rn(x[4 * q + 0], c3.x, a3); a3 = __fmaf_rn(x[4 * q + 1], c3.y, a3);
      a3 = __fmaf_rn(x[4 * q + 2], c3.z, a3); a3 = __fmaf_rn(x[4 * q + 3], c3.w, a3);
    }
    float4 cn = *(const float4*)(cnorm + k0);
    float s;
    s = __fadd_rn(__fsub_rn(xn, __fmul_rn(2.0f, a0)), cn.x);
    if (isnan_bits32(s)) { if (firstnan == 0x7fffffff) firstnan = k0; }
    else if (bestk < 0 || s < best) { best = s; bestk = k0; }
    s = __fadd_rn(__fsub_rn(xn, __fmul_rn(2.0f, a1)), cn.y);
    if (isnan_bits32(s)) { if (firstnan == 0x7fffffff) firstnan = k0 + 1; }
    else if (bestk < 0 || s < best) { best = s; bestk = k0 + 1; }
    s = __fadd_rn(__fsub_rn(xn, __fmul_rn(2.0f, a2)), cn.z);
    if (isnan_bits32(s)) { if (firstnan == 0x7fffffff) firstnan = k0 + 2; }
    else if (bestk < 0 || s < best) { best = s; bestk = k0 + 2; }
    s = __fadd_rn(__fsub_rn(xn, __fmul_rn(2.0f, a3)), cn.w);
    if (isnan_bits32(s)) { if (firstnan == 0x7fffffff) firstnan = k0 + 3; }
    else if (bestk < 0 || s < best) { best = s; bestk = k0 + 3; }
  }
  labels[p] = (firstnan != 0x7fffffff) ? firstnan : bestk;
}

// ======== deterministic counting-sort update (unchanged from passing R8-R11) ========

__global__ void k_hist(const int* __restrict__ labels, int* __restrict__ counts) {
  __shared__ int hist[KCL];
  int c = blockIdx.x, t = threadIdx.x;
  hist[t] = 0; hist[t + 256] = 0;
  __syncthreads();
  int lab = labels[c * CHS + t];
  atomicAdd(&hist[lab], 1);
  __syncthreads();
  counts[(size_t)t * NCH + c] = hist[t];
  counts[(size_t)(t + 256) * NCH + c] = hist[t + 256];
}

__global__ void k_scan_chunks(const int* __restrict__ counts, int* __restrict__ cbase,
                              int* __restrict__ total) {
  __shared__ int s[NCH];
  int k = blockIdx.x, c = threadIdx.x;
  int v = counts[(size_t)k * NCH + c];
  s[c] = v;
  __syncthreads();
  for (int off = 1; off < NCH; off <<= 1) {
    int t = (c >= off) ? s[c - off] : 0;
    __syncthreads();
    s[c] += t;
    __syncthreads();
  }
  cbase[(size_t)k * NCH + c] = s[c] - v;
  if (c == NCH - 1) total[k] = s[c];
}

__global__ void k_scan_k(const int* __restrict__ total, int* __restrict__ offset) {
  __shared__ int s[KCL];
  int c = threadIdx.x;
  int v = total[c];
  s[c] = v;
  __syncthreads();
  for (int off = 1; off < KCL; off <<= 1) {
    int t = (c >= off) ? s[c - off] : 0;
    __syncthreads();
    s[c] += t;
    __syncthreads();
  }
  offset[c] = s[c] - v;
}

__global__ void k_scatter(const int* __restrict__ labels, const int* __restrict__ cbase,
                          const int* __restrict__ offset, int* __restrict__ list) {
  __shared__ int lab[CHS];
  int c = blockIdx.x, t = threadIdx.x;
  int L = labels[c * CHS + t];
  lab[t] = L;
  __syncthreads();
  int rank = 0;
  for (int j = 0; j < t; ++j) rank += (lab[j] == L);
  list[offset[L] + cbase[(size_t)L * NCH + c] + rank] = c * CHS + t;
}

__global__ void k_sum(const float* __restrict__ X, const int* __restrict__ list,
                      const int* __restrict__ offset, const int* __restrict__ total,
                      float* __restrict__ C, float* __restrict__ cnorm) {
  int k = blockIdx.x, d = threadIdx.x;
  int n = total[k], off = offset[k];
  float acc = 0.0f;
  int t = 0;
  for (; t + 4 <= n; t += 4) {
    int i0 = list[off + t + 0], i1 = list[off + t + 1];
    int i2 = list[off + t + 2], i3 = list[off + t + 3];
    float x0 = X[(size_t)i0 * DI + d], x1 = X[(size_t)i1 * DI + d];
    float x2 = X[(size_t)i2 * DI + d], x3 = X[(size_t)i3 * DI + d];
    acc = __fadd_rn(acc, x0); acc = __fadd_rn(acc, x1);
    acc = __fadd_rn(acc, x2); acc = __fadd_rn(acc, x3);
  }
  for (; t < n; ++t) {
    int i = list[off + t];
    acc = __fadd_rn(acc, X[(size_t)i * DI + d]);
  }
  float cv = (n == 0) ? __uint_as_float(0x7FC00000u) : __fdiv_rn(acc, (float)n);
  C[(size_t)k * DI + d] = cv;
  __shared__ float row[DI];
  row[d] = cv;
  __syncthreads();
  if (d == 0) cnorm[k] = np_pairwise128_sq(row);
}

extern "C" void kernel_launch(void* const* d_in, const int* in_sizes, int n_in,
                              void* d_out, int out_size, void* d_ws, size_t ws_size,
                              hipStream_t stream) {
  (void)in_sizes; (void)n_in; (void)out_size; (void)ws_size;
  const float* X = (const float*)d_in[0];
  int* out = (int*)d_out;
  char* ws = (char*)d_ws;
  float* C      = (float*)(ws);                              // 256 KB
  float* cnorm  = (float*)(ws + 262144);                     // 2 KB
  float* xnorm  = (float*)(ws + 264192);                     // 1 MB
  int*   counts = (int*)(ws + 264192 + 1048576);             // 2 MB
  int*   cbase  = (int*)(ws + 264192 + 1048576 + 2097152);   // 2 MB
  int*   total  = (int*)(ws + 264192 + 1048576 + 2 * 2097152);         // 2 KB
  int*   offset = (int*)(ws + 264192 + 1048576 + 2 * 2097152 + 2048);  // 2 KB
  int*   list   = (int*)(ws + 264192 + 1048576 + 2 * 2097152 + 4096);  // 1 MB

  k_init<<<KCL, DI, 0, stream>>>(X, C, cnorm);
  k_xnorm<<<NP / 256, 256, 0, stream>>>(X, xnorm);
  for (int t = 0; t < NIT; ++t) {
    k_assign_r<<<NP / 256, 256, 0, stream>>>(X, C, cnorm, xnorm, out);
    if (t < NIT - 1) {
      k_hist<<<NCH, CHS, 0, stream>>>(out, counts);
      k_scan_chunks<<<KCL, NCH, 0, stream>>>(counts, cbase, total);
      k_scan_k<<<1, KCL, 0, stream>>>(total, offset);
      k_scatter<<<NCH, CHS, 0, stream>>>(out, cbase, offset, list);
      k_sum<<<KCL, DI, 0, stream>>>(X, list, offset, total, C, cnorm);
    }
  }
}

// Round 13
// 20195.790 us; speedup vs baseline: 1.0052x; 1.0052x over previous
//
#include <hip/hip_runtime.h>

#define NP 262144
#define DI 128
#define KCL 512
#define NIT 10
#define NCH 1024      // chunks for the counting sort
#define CHS 256       // points per chunk (NCH*CHS == NP)

// Fast-math-immune fp32 NaN test.
__device__ __forceinline__ bool isnan_bits32(float x) {
  unsigned b = __float_as_uint(x);
  return (b & 0x7FFFFFFFu) > 0x7F800000u;
}

// numpy pairwise_sum of v[i]*v[i] for n=128 (numpy's 8-accumulator unrolled path).
__device__ __forceinline__ float np_pairwise128_sq(const float* v) {
  float r[8];
  #pragma unroll
  for (int j = 0; j < 8; ++j) r[j] = __fmul_rn(v[j], v[j]);
  #pragma unroll
  for (int t = 1; t < 16; ++t)
    #pragma unroll
    for (int j = 0; j < 8; ++j)
      r[j] = __fadd_rn(r[j], __fmul_rn(v[8 * t + j], v[8 * t + j]));
  float t01 = __fadd_rn(r[0], r[1]), t23 = __fadd_rn(r[2], r[3]);
  float t45 = __fadd_rn(r[4], r[5]), t67 = __fadd_rn(r[6], r[7]);
  return __fadd_rn(__fadd_rn(t01, t23), __fadd_rn(t45, t67));
}

// ---------------- init: C0 = X[:512]; cnorm[k] = np-pairwise of c*c ----------------
__global__ void k_init(const float* __restrict__ X, float* __restrict__ C,
                       float* __restrict__ cnorm) {
  int k = blockIdx.x, d = threadIdx.x;
  float v = X[(size_t)k * DI + d];
  C[(size_t)k * DI + d] = v;
  __shared__ float row[DI];
  row[d] = v;
  __syncthreads();
  if (d == 0) cnorm[k] = np_pairwise128_sq(row);
}

// ---------------- xnorm: once per run (X constant). Streaming 8-acc pairwise. ----------
__global__ void k_xnorm(const float* __restrict__ X, float* __restrict__ xnorm) {
  const int p = blockIdx.x * 256 + threadIdx.x;
  const float4* X4 = (const float4*)X + (size_t)p * 32;
  float r[8];
  {
    float4 q0 = X4[0], q1 = X4[1];
    r[0] = __fmul_rn(q0.x, q0.x); r[1] = __fmul_rn(q0.y, q0.y);
    r[2] = __fmul_rn(q0.z, q0.z); r[3] = __fmul_rn(q0.w, q0.w);
    r[4] = __fmul_rn(q1.x, q1.x); r[5] = __fmul_rn(q1.y, q1.y);
    r[6] = __fmul_rn(q1.z, q1.z); r[7] = __fmul_rn(q1.w, q1.w);
  }
  #pragma unroll
  for (int t = 1; t < 16; ++t) {
    float4 q0 = X4[2 * t], q1 = X4[2 * t + 1];
    r[0] = __fadd_rn(r[0], __fmul_rn(q0.x, q0.x));
    r[1] = __fadd_rn(r[1], __fmul_rn(q0.y, q0.y));
    r[2] = __fadd_rn(r[2], __fmul_rn(q0.z, q0.z));
    r[3] = __fadd_rn(r[3], __fmul_rn(q0.w, q0.w));
    r[4] = __fadd_rn(r[4], __fmul_rn(q1.x, q1.x));
    r[5] = __fadd_rn(r[5], __fmul_rn(q1.y, q1.y));
    r[6] = __fadd_rn(r[6], __fmul_rn(q1.z, q1.z));
    r[7] = __fadd_rn(r[7], __fmul_rn(q1.w, q1.w));
  }
  float t01 = __fadd_rn(r[0], r[1]), t23 = __fadd_rn(r[2], r[3]);
  float t45 = __fadd_rn(r[4], r[5]), t67 = __fadd_rn(r[6], r[7]);
  xnorm[p] = __fadd_rn(__fadd_rn(t01, t23), __fadd_rn(t45, t67));
}

// ---------------- assignment: x PINNED in registers via opaque asm; KU=4 chains ----------
// Same arithmetic as R10/R12 (passed, absmax 0). The asm "+v" tie makes each x[i] the
// output of an opaque op -> compiler cannot rematerialize the global loads inside the
// k-loop; all 128 values stay VGPR-resident.
__global__ __launch_bounds__(256, 1)
void k_assign_p(const float* __restrict__ X, const float* __restrict__ C,
                const float* __restrict__ cnorm, const float* __restrict__ xnorm,
                int* __restrict__ labels) {
  const int p = blockIdx.x * 256 + threadIdx.x;
  const float4* X4 = (const float4*)X + (size_t)p * 32;
  float x[DI];
  #pragma unroll
  for (int q = 0; q < 32; ++q) {
    float4 v = X4[q];
    x[4 * q + 0] = v.x; x[4 * q + 1] = v.y;
    x[4 * q + 2] = v.z; x[4 * q + 3] = v.w;
  }
  #pragma unroll
  for (int i = 0; i < DI; ++i) asm volatile("" : "+v"(x[i]));   // pin: no remat
  const float xn = xnorm[p];

  float best = 0.0f;
  int bestk = -1;
  int firstnan = 0x7fffffff;
  for (int k0 = 0; k0 < KCL; k0 += 4) {
    const float* C0 = C + (size_t)k0 * DI;
    float a0 = 0.0f, a1 = 0.0f, a2 = 0.0f, a3 = 0.0f;
    #pragma unroll
    for (int q = 0; q < 32; ++q) {
      float4 c0 = *(const float4*)(C0 + 0 * DI + 4 * q);
      float4 c1 = *(const float4*)(C0 + 1 * DI + 4 * q);
      float4 c2 = *(const float4*)(C0 + 2 * DI + 4 * q);
      float4 c3 = *(const float4*)(C0 + 3 * DI + 4 * q);
      a0 = __fmaf_rn(x[4 * q + 0], c0.x, a0); a0 = __fmaf_rn(x[4 * q + 1], c0.y, a0);
      a0 = __fmaf_rn(x[4 * q + 2], c0.z, a0); a0 = __fmaf_rn(x[4 * q + 3], c0.w, a0);
      a1 = __fmaf_rn(x[4 * q + 0], c1.x, a1); a1 = __fmaf_rn(x[4 * q + 1], c1.y, a1);
      a1 = __fmaf_rn(x[4 * q + 2], c1.z, a1); a1 = __fmaf_rn(x[4 * q + 3], c1.w, a1);
      a2 = __fmaf_rn(x[4 * q + 0], c2.x, a2); a2 = __fmaf_rn(x[4 * q + 1], c2.y, a2);
      a2 = __fmaf_rn(x[4 * q + 2], c2.z, a2); a2 = __fmaf_rn(x[4 * q + 3], c2.w, a2);
      a3 = __fmaf_rn(x[4 * q + 0], c3.x, a3); a3 = __fmaf_rn(x[4 * q + 1], c3.y, a3);
      a3 = __fmaf_rn(x[4 * q + 2], c3.z, a3); a3 = __fmaf_rn(x[4 * q + 3], c3.w, a3);
    }
    float4 cn = *(const float4*)(cnorm + k0);
    float s;
    s = __fadd_rn(__fsub_rn(xn, __fmul_rn(2.0f, a0)), cn.x);
    if (isnan_bits32(s)) { if (firstnan == 0x7fffffff) firstnan = k0; }
    else if (bestk < 0 || s < best) { best = s; bestk = k0; }
    s = __fadd_rn(__fsub_rn(xn, __fmul_rn(2.0f, a1)), cn.y);
    if (isnan_bits32(s)) { if (firstnan == 0x7fffffff) firstnan = k0 + 1; }
    else if (bestk < 0 || s < best) { best = s; bestk = k0 + 1; }
    s = __fadd_rn(__fsub_rn(xn, __fmul_rn(2.0f, a2)), cn.z);
    if (isnan_bits32(s)) { if (firstnan == 0x7fffffff) firstnan = k0 + 2; }
    else if (bestk < 0 || s < best) { best = s; bestk = k0 + 2; }
    s = __fadd_rn(__fsub_rn(xn, __fmul_rn(2.0f, a3)), cn.w);
    if (isnan_bits32(s)) { if (firstnan == 0x7fffffff) firstnan = k0 + 3; }
    else if (bestk < 0 || s < best) { best = s; bestk = k0 + 3; }
  }
  labels[p] = (firstnan != 0x7fffffff) ? firstnan : bestk;
}

// ======== deterministic counting-sort update (unchanged from passing R8-R12) ========

__global__ void k_hist(const int* __restrict__ labels, int* __restrict__ counts) {
  __shared__ int hist[KCL];
  int c = blockIdx.x, t = threadIdx.x;
  hist[t] = 0; hist[t + 256] = 0;
  __syncthreads();
  int lab = labels[c * CHS + t];
  atomicAdd(&hist[lab], 1);
  __syncthreads();
  counts[(size_t)t * NCH + c] = hist[t];
  counts[(size_t)(t + 256) * NCH + c] = hist[t + 256];
}

__global__ void k_scan_chunks(const int* __restrict__ counts, int* __restrict__ cbase,
                              int* __restrict__ total) {
  __shared__ int s[NCH];
  int k = blockIdx.x, c = threadIdx.x;
  int v = counts[(size_t)k * NCH + c];
  s[c] = v;
  __syncthreads();
  for (int off = 1; off < NCH; off <<= 1) {
    int t = (c >= off) ? s[c - off] : 0;
    __syncthreads();
    s[c] += t;
    __syncthreads();
  }
  cbase[(size_t)k * NCH + c] = s[c] - v;
  if (c == NCH - 1) total[k] = s[c];
}

__global__ void k_scan_k(const int* __restrict__ total, int* __restrict__ offset) {
  __shared__ int s[KCL];
  int c = threadIdx.x;
  int v = total[c];
  s[c] = v;
  __syncthreads();
  for (int off = 1; off < KCL; off <<= 1) {
    int t = (c >= off) ? s[c - off] : 0;
    __syncthreads();
    s[c] += t;
    __syncthreads();
  }
  offset[c] = s[c] - v;
}

__global__ void k_scatter(const int* __restrict__ labels, const int* __restrict__ cbase,
                          const int* __restrict__ offset, int* __restrict__ list) {
  __shared__ int lab[CHS];
  int c = blockIdx.x, t = threadIdx.x;
  int L = labels[c * CHS + t];
  lab[t] = L;
  __syncthreads();
  int rank = 0;
  for (int j = 0; j < t; ++j) rank += (lab[j] == L);
  list[offset[L] + cbase[(size_t)L * NCH + c] + rank] = c * CHS + t;
}

__global__ void k_sum(const float* __restrict__ X, const int* __restrict__ list,
                      const int* __restrict__ offset, const int* __restrict__ total,
                      float* __restrict__ C, float* __restrict__ cnorm) {
  int k = blockIdx.x, d = threadIdx.x;
  int n = total[k], off = offset[k];
  float acc = 0.0f;
  int t = 0;
  for (; t + 4 <= n; t += 4) {
    int i0 = list[off + t + 0], i1 = list[off + t + 1];
    int i2 = list[off + t + 2], i3 = list[off + t + 3];
    float x0 = X[(size_t)i0 * DI + d], x1 = X[(size_t)i1 * DI + d];
    float x2 = X[(size_t)i2 * DI + d], x3 = X[(size_t)i3 * DI + d];
    acc = __fadd_rn(acc, x0); acc = __fadd_rn(acc, x1);
    acc = __fadd_rn(acc, x2); acc = __fadd_rn(acc, x3);
  }
  for (; t < n; ++t) {
    int i = list[off + t];
    acc = __fadd_rn(acc, X[(size_t)i * DI + d]);
  }
  float cv = (n == 0) ? __uint_as_float(0x7FC00000u) : __fdiv_rn(acc, (float)n);
  C[(size_t)k * DI + d] = cv;
  __shared__ float row[DI];
  row[d] = cv;
  __syncthreads();
  if (d == 0) cnorm[k] = np_pairwise128_sq(row);
}

extern "C" void kernel_launch(void* const* d_in, const int* in_sizes, int n_in,
                              void* d_out, int out_size, void* d_ws, size_t ws_size,
                              hipStream_t stream) {
  (void)in_sizes; (void)n_in; (void)out_size; (void)ws_size;
  const float* X = (const float*)d_in[0];
  int* out = (int*)d_out;
  char* ws = (char*)d_ws;
  float* C      = (float*)(ws);                              // 256 KB
  float* cnorm  = (float*)(ws + 262144);                     // 2 KB
  float* xnorm  = (float*)(ws + 264192);                     // 1 MB
  int*   counts = (int*)(ws + 264192 + 1048576);             // 2 MB
  int*   cbase  = (int*)(ws + 264192 + 1048576 + 2097152);   // 2 MB
  int*   total  = (int*)(ws + 264192 + 1048576 + 2 * 2097152);         // 2 KB
  int*   offset = (int*)(ws + 264192 + 1048576 + 2 * 2097152 + 2048);  // 2 KB
  int*   list   = (int*)(ws + 264192 + 1048576 + 2 * 2097152 + 4096);  // 1 MB

  k_init<<<KCL, DI, 0, stream>>>(X, C, cnorm);
  k_xnorm<<<NP / 256, 256, 0, stream>>>(X, xnorm);
  for (int t = 0; t < NIT; ++t) {
    k_assign_p<<<NP / 256, 256, 0, stream>>>(X, C, cnorm, xnorm, out);
    if (t < NIT - 1) {
      k_hist<<<NCH, CHS, 0, stream>>>(out, counts);
      k_scan_chunks<<<KCL, NCH, 0, stream>>>(counts, cbase, total);
      k_scan_k<<<1, KCL, 0, stream>>>(total, offset);
      k_scatter<<<NCH, CHS, 0, stream>>>(out, cbase, offset, list);
      k_sum<<<KCL, DI, 0, stream>>>(X, list, offset, total, C, cnorm);
    }
  }
}